// Round 2
// 1563.394 us; speedup vs baseline: 1.0063x; 1.0063x over previous
//
#include <hip/hip_runtime.h>
#include <cstdint>
#include <cstddef>

#define HIDDEN 2048
#define INTER 8192
#define NTOK 8192
#define RET 128
#define NKEYS 64
#define TOPK 8

typedef __bf16 bf16_t;
typedef bf16_t bf16x8 __attribute__((ext_vector_type(8)));
typedef float floatx4 __attribute__((ext_vector_type(4)));

#define BARRIER() asm volatile("s_barrier" ::: "memory")
#define WAIT_LGKM0()                                     \
  do {                                                   \
    asm volatile("s_waitcnt lgkmcnt(0)" ::: "memory");   \
    __builtin_amdgcn_sched_barrier(0);                   \
  } while (0)
#define WAIT_VM8() asm volatile("s_waitcnt vmcnt(8)" ::: "memory")
#define WAIT_VM4() asm volatile("s_waitcnt vmcnt(4)" ::: "memory")
#define WAIT_VM0() asm volatile("s_waitcnt vmcnt(0)" ::: "memory")

// Tile-end drain: count must track loads actually in flight. Steady state has
// 12 outstanding (tiles t+1..t+3, 4 each) -> vmcnt(8) drains tile t+1. In the
// endgame no new stages are issued, so the wait must tighten 8 -> 4 -> 0 or
// the last two tiles read unlanded LDS (R1's correctness bug).
__device__ inline void tile_end_wait(int rem) {
  if (rem >= 3) WAIT_VM8();
  else if (rem == 2) WAIT_VM4();
  else if (rem == 1) WAIT_VM0();
}

__device__ inline unsigned short f2bf(float f) {
  union { float f; unsigned u; } v; v.f = f;
  unsigned r = v.u + 0x7FFFu + ((v.u >> 16) & 1u);  // RNE
  return (unsigned short)(r >> 16);
}

// async global->LDS, 16B per lane. lds must be the wave-uniform base; HW puts
// lane i's 16B at base + i*16.
__device__ inline void gld_lds16(unsigned short* lds, const unsigned short* g) {
  auto* l3 = reinterpret_cast<__attribute__((address_space(3))) unsigned int*>(
      reinterpret_cast<uintptr_t>(lds));
  auto* g1 = reinterpret_cast<const __attribute__((address_space(1))) unsigned int*>(
      reinterpret_cast<uintptr_t>(g));
  __builtin_amdgcn_global_load_lds(g1, l3, 16, 0, 0);
}

// XCD-aware block remap: contiguous column band per XCD, serpentine traversal.
// Only applies when gridDim.x % 8 == 0.
__device__ inline void xcd_map(int gx, int gy, int& bx, int& by) {
  if ((gx & 7) != 0) return;
  int lin = by * gx + bx;
  int W = gx >> 3;
  int xcd = lin & 7;
  int j = lin >> 3;
  int r = j / W, c = j % W;
  if (r & 1) c = W - 1 - c;
  bx = xcd * W + c;
  by = r;
}

// Stage one 256-row x 32-col bf16 operand tile into LDS (linear dest,
// inverse-swizzled source). Swizzle: data chunk cc lives at slot
// cc ^ (row&3) ^ ((row>>2)&3) -> frag reads are bank-uniform (2 lanes/slot).
__device__ inline void stage_op256(unsigned short* ldsbuf, const unsigned short* g,
                                   int rows0, int K, int kt, int tid, int wid) {
#pragma unroll
  for (int i = 0; i < 2; ++i) {
    int c = i * 512 + tid;
    int row = c >> 2;
    int cc = (c & 3) ^ (row & 3) ^ ((row >> 2) & 3);
    gld_lds16(ldsbuf + (size_t)(i * 512 + wid * 64) * 8,
              g + (size_t)(rows0 + row) * K + kt + cc * 8);
  }
}
// 128-row variant (one 512-thread sweep).
__device__ inline void stage_op128(unsigned short* ldsbuf, const unsigned short* g,
                                   int rows0, int K, int kt, int tid, int wid) {
  int row = tid >> 2;
  int cc = (tid & 3) ^ (row & 3) ^ ((row >> 2) & 3);
  gld_lds16(ldsbuf + (size_t)(wid * 64) * 8,
            g + (size_t)(rows0 + row) * K + kt + cc * 8);
}

// ---------------- fp32 -> bf16 convert (contiguous) ----------------
__global__ __launch_bounds__(256) void cvt_bf16(const float* __restrict__ in,
                                                unsigned short* __restrict__ out,
                                                int count4) {
  for (int i = blockIdx.x * blockDim.x + threadIdx.x; i < count4;
       i += gridDim.x * blockDim.x) {
    float4 v = reinterpret_cast<const float4*>(in)[i];
    ushort4 o;
    o.x = f2bf(v.x); o.y = f2bf(v.y); o.z = f2bf(v.z); o.w = f2bf(v.w);
    reinterpret_cast<ushort4*>(out)[i] = o;
  }
}

// ---------------- fp32 [R][C] -> bf16 [C][R] transpose-convert ----------------
__global__ __launch_bounds__(256) void transpose_cvt(const float* __restrict__ in,
                                                     unsigned short* __restrict__ out,
                                                     int R, int C) {
  __shared__ float tile[32][33];
  int c0 = blockIdx.x * 32, r0 = blockIdx.y * 32;
  int tx = threadIdx.x, ty = threadIdx.y;  // block (32,8)
#pragma unroll
  for (int it = 0; it < 4; ++it)
    tile[ty + it * 8][tx] = in[(size_t)(r0 + ty + it * 8) * C + c0 + tx];
  __syncthreads();
#pragma unroll
  for (int it = 0; it < 4; ++it)
    out[(size_t)(c0 + ty + it * 8) * R + r0 + tx] = f2bf(tile[tx][ty + it * 8]);
}

// ---------------- legacy 128x128 bf16 GEMM (kept for the small Q proj) -------
enum { EPI_F32 = 0, EPI_ADDF32 = 3 };

template <int MODE>
__global__ __launch_bounds__(256) void gemm_bt(const unsigned short* __restrict__ A,
                                               const unsigned short* __restrict__ B,
                                               float* __restrict__ Cf,
                                               int M, int N, int K) {
  __shared__ unsigned short As[128 * 64];
  __shared__ unsigned short Bs[128 * 64];
  const int tid = threadIdx.x;
  const int lane = tid & 63, wid = tid >> 6;
  const int wm = wid >> 1, wn = wid & 1;
  int bx = blockIdx.x, by = blockIdx.y;
  xcd_map(gridDim.x, gridDim.y, bx, by);
  const int m0 = by * 128, n0 = bx * 128;
  const int lr = lane & 15, q = lane >> 4;
  const int swz = lr & 7;

  floatx4 acc[4][4];
#pragma unroll
  for (int i = 0; i < 4; ++i)
#pragma unroll
    for (int j = 0; j < 4; ++j) acc[i][j] = (floatx4){0.f, 0.f, 0.f, 0.f};

  for (int k0 = 0; k0 < K; k0 += 64) {
#pragma unroll
    for (int s = 0; s < 4; ++s) {
      int c = s * 256 + wid * 64 + lane;
      int row = c >> 3, cc = (c & 7) ^ (row & 7);
      gld_lds16(&As[(s * 256 + wid * 64) * 8],
                A + (size_t)(m0 + row) * K + k0 + cc * 8);
      gld_lds16(&Bs[(s * 256 + wid * 64) * 8],
                B + (size_t)(n0 + row) * K + k0 + cc * 8);
    }
    __syncthreads();
#pragma unroll
    for (int kc = 0; kc < 2; ++kc) {
      const int coff = ((kc * 4 + q) ^ swz) * 8;
      bf16x8 af[4], bfv[4];
#pragma unroll
      for (int t = 0; t < 4; ++t) {
        af[t] = *reinterpret_cast<const bf16x8*>(
            &As[(wm * 64 + t * 16 + lr) * 64 + coff]);
        bfv[t] = *reinterpret_cast<const bf16x8*>(
            &Bs[(wn * 64 + t * 16 + lr) * 64 + coff]);
      }
#pragma unroll
      for (int i = 0; i < 4; ++i)
#pragma unroll
        for (int j = 0; j < 4; ++j)
          acc[i][j] = __builtin_amdgcn_mfma_f32_16x16x32_bf16(af[i], bfv[j],
                                                              acc[i][j], 0, 0, 0);
    }
    __syncthreads();
  }

#pragma unroll
  for (int i = 0; i < 4; ++i) {
    int rbase = m0 + wm * 64 + i * 16 + q * 4;
#pragma unroll
    for (int j = 0; j < 4; ++j) {
      int col = n0 + wn * 64 + j * 16 + lr;
#pragma unroll
      for (int r = 0; r < 4; ++r) {
        size_t idx = (size_t)(rbase + r) * N + col;
        float v = acc[i][j][r];
        if (MODE == EPI_F32) Cf[idx] = v;
        else Cf[idx] = v + Cf[idx];
      }
    }
  }
}

// ---------------- 256x256 deep-pipelined bf16 GEMM: C[M,N] (+)= A[M,K]*B[N,K]^T
// BK=32, 8 waves (2Mx4N, 128x64/wave), ring-4 LDS K-tile buffers (128 KiB),
// 2 phases/tile, staging 3 tiles ahead, counted vmcnt once per tile (never 0
// in steady state). Liveness: buffer t+3 == buffer t-1, whose last ds_reads
// were drained (lgkmcnt(0)) before tile t-1's end barrier, so stage issues in
// tile t are race-free; the end-of-tile counted wait guarantees tile t+1
// (issued during t-2) has landed. Endgame tightens the count 8->4->0.
template <int MODE>
__global__ __launch_bounds__(512, 2) void gemm256(const unsigned short* __restrict__ A,
                                                  const unsigned short* __restrict__ B,
                                                  float* __restrict__ Cf,
                                                  int N, int K) {
  extern __shared__ unsigned short sm[];
  const int tid = threadIdx.x;
  const int lane = tid & 63, wid = tid >> 6;
  const int wm = wid >> 2, wn = wid & 3;
  int bx = blockIdx.x, by = blockIdx.y;
  xcd_map(gridDim.x, gridDim.y, bx, by);
  const int m0 = by * 256, n0 = bx * 256;
  const int lr = lane & 15, q = lane >> 4;
  const int swz = (lr & 3) ^ ((lr >> 2) & 3);
  const int coff = (q ^ swz) * 8;
  unsigned short* Abase = sm;            // 4 x 8192 ushort
  unsigned short* Bbase = sm + 32768;    // 4 x 8192 ushort
  const int NT = K >> 5;

  floatx4 acc[8][4];
#pragma unroll
  for (int i = 0; i < 8; ++i)
#pragma unroll
    for (int j = 0; j < 4; ++j) acc[i][j] = (floatx4){0.f, 0.f, 0.f, 0.f};

  // prologue: stage tiles 0..2; vmcnt(8) drains tile 0, leaves 1,2 in flight.
#pragma unroll
  for (int tt = 0; tt < 3; ++tt) {
    stage_op256(Abase + tt * 8192, A, m0, K, tt * 32, tid, wid);
    stage_op256(Bbase + tt * 8192, B, n0, K, tt * 32, tid, wid);
  }
  WAIT_VM8();
  BARRIER();

  for (int t = 0; t < NT; ++t) {
    const int buf = t & 3;
    const unsigned short* As = Abase + buf * 8192;
    const unsigned short* Bs = Bbase + buf * 8192;
    bf16x8 af[4], bfv[4];
    // ---- phase 0: m-frags 0..3, all n-frags ----
#pragma unroll
    for (int m = 0; m < 4; ++m)
      af[m] = *reinterpret_cast<const bf16x8*>(
          &As[(wm * 128 + m * 16 + lr) * 32 + coff]);
#pragma unroll
    for (int n = 0; n < 4; ++n)
      bfv[n] = *reinterpret_cast<const bf16x8*>(
          &Bs[(wn * 64 + n * 16 + lr) * 32 + coff]);
    if (t + 3 < NT)
      stage_op256(Abase + ((t + 3) & 3) * 8192, A, m0, K, (t + 3) * 32, tid, wid);
    BARRIER();
    WAIT_LGKM0();
    __builtin_amdgcn_s_setprio(1);
#pragma unroll
    for (int m = 0; m < 4; ++m)
#pragma unroll
      for (int n = 0; n < 4; ++n)
        acc[m][n] = __builtin_amdgcn_mfma_f32_16x16x32_bf16(af[m], bfv[n],
                                                            acc[m][n], 0, 0, 0);
    __builtin_amdgcn_s_setprio(0);
    __builtin_amdgcn_sched_barrier(0);
    BARRIER();
    // ---- phase 1: m-frags 4..7, reuse bfv ----
#pragma unroll
    for (int m = 0; m < 4; ++m)
      af[m] = *reinterpret_cast<const bf16x8*>(
          &As[(wm * 128 + (m + 4) * 16 + lr) * 32 + coff]);
    if (t + 3 < NT)
      stage_op256(Bbase + ((t + 3) & 3) * 8192, B, n0, K, (t + 3) * 32, tid, wid);
    BARRIER();
    WAIT_LGKM0();
    __builtin_amdgcn_s_setprio(1);
#pragma unroll
    for (int m = 0; m < 4; ++m)
#pragma unroll
      for (int n = 0; n < 4; ++n)
        acc[m + 4][n] = __builtin_amdgcn_mfma_f32_16x16x32_bf16(af[m], bfv[n],
                                                                acc[m + 4][n], 0, 0, 0);
    __builtin_amdgcn_s_setprio(0);
    __builtin_amdgcn_sched_barrier(0);
    tile_end_wait(NT - 1 - t);
    BARRIER();
  }

  // epilogue: C/D layout col=lane&15, row=(lane>>4)*4+reg
#pragma unroll
  for (int m = 0; m < 8; ++m) {
    int rbase = m0 + wm * 128 + m * 16 + q * 4;
#pragma unroll
    for (int n = 0; n < 4; ++n) {
      int col = n0 + wn * 64 + n * 16 + lr;
#pragma unroll
      for (int r = 0; r < 4; ++r) {
        size_t idx = (size_t)(rbase + r) * N + col;
        float v = acc[m][n][r];
        if (MODE == EPI_F32) Cf[idx] = v;
        else Cf[idx] = v + Cf[idx];  // += expert states already in d_out
      }
    }
  }
}

// ---------------- fused gate+up with the same deep-pipelined schedule --------
// 256x128 tile, 8 waves (4Mx2N, 64x64/wave so accg+accu = 128 VGPRs), BK=32,
// ring-4 buffers for A (256x32) + Bg + Bu (128x32 each) = 128 KiB LDS.
__global__ __launch_bounds__(512, 2) void gateup256(const unsigned short* __restrict__ A,
                                                    const unsigned short* __restrict__ Bg,
                                                    const unsigned short* __restrict__ Bu,
                                                    unsigned short* __restrict__ H,
                                                    int N, int K) {
  extern __shared__ unsigned short sm[];
  const int tid = threadIdx.x;
  const int lane = tid & 63, wid = tid >> 6;
  const int wm = wid >> 1, wn = wid & 1;
  int bx = blockIdx.x, by = blockIdx.y;
  xcd_map(gridDim.x, gridDim.y, bx, by);
  const int m0 = by * 256, n0 = bx * 128;
  const int lr = lane & 15, q = lane >> 4;
  const int swz = (lr & 3) ^ ((lr >> 2) & 3);
  const int coff = (q ^ swz) * 8;
  unsigned short* Abase = sm;             // 4 x 8192
  unsigned short* Bgbase = sm + 32768;    // 4 x 4096
  unsigned short* Bubase = sm + 49152;    // 4 x 4096
  const int NT = K >> 5;

  floatx4 accg[4][4], accu[4][4];
#pragma unroll
  for (int i = 0; i < 4; ++i)
#pragma unroll
    for (int j = 0; j < 4; ++j) {
      accg[i][j] = (floatx4){0.f, 0.f, 0.f, 0.f};
      accu[i][j] = (floatx4){0.f, 0.f, 0.f, 0.f};
    }

#pragma unroll
  for (int tt = 0; tt < 3; ++tt) {
    stage_op256(Abase + tt * 8192, A, m0, K, tt * 32, tid, wid);
    stage_op128(Bgbase + tt * 4096, Bg, n0, K, tt * 32, tid, wid);
    stage_op128(Bubase + tt * 4096, Bu, n0, K, tt * 32, tid, wid);
  }
  WAIT_VM8();
  BARRIER();

  for (int t = 0; t < NT; ++t) {
    const int buf = t & 3;
    const unsigned short* As = Abase + buf * 8192;
    const unsigned short* Bgs = Bgbase + buf * 4096;
    const unsigned short* Bus = Bubase + buf * 4096;
    bf16x8 af[2], bg[4], bu[4];
    // ---- phase 0: m-frags 0..1, all n-frags, both operators ----
#pragma unroll
    for (int m = 0; m < 2; ++m)
      af[m] = *reinterpret_cast<const bf16x8*>(
          &As[(wm * 64 + m * 16 + lr) * 32 + coff]);
#pragma unroll
    for (int n = 0; n < 4; ++n) {
      bg[n] = *reinterpret_cast<const bf16x8*>(
          &Bgs[(wn * 64 + n * 16 + lr) * 32 + coff]);
      bu[n] = *reinterpret_cast<const bf16x8*>(
          &Bus[(wn * 64 + n * 16 + lr) * 32 + coff]);
    }
    if (t + 3 < NT)
      stage_op256(Abase + ((t + 3) & 3) * 8192, A, m0, K, (t + 3) * 32, tid, wid);
    BARRIER();
    WAIT_LGKM0();
    __builtin_amdgcn_s_setprio(1);
#pragma unroll
    for (int m = 0; m < 2; ++m)
#pragma unroll
      for (int n = 0; n < 4; ++n) {
        accg[m][n] = __builtin_amdgcn_mfma_f32_16x16x32_bf16(af[m], bg[n],
                                                             accg[m][n], 0, 0, 0);
        accu[m][n] = __builtin_amdgcn_mfma_f32_16x16x32_bf16(af[m], bu[n],
                                                             accu[m][n], 0, 0, 0);
      }
    __builtin_amdgcn_s_setprio(0);
    __builtin_amdgcn_sched_barrier(0);
    BARRIER();
    // ---- phase 1: m-frags 2..3, reuse bg/bu ----
#pragma unroll
    for (int m = 0; m < 2; ++m)
      af[m] = *reinterpret_cast<const bf16x8*>(
          &As[(wm * 64 + (m + 2) * 16 + lr) * 32 + coff]);
    if (t + 3 < NT) {
      stage_op128(Bgbase + ((t + 3) & 3) * 4096, Bg, n0, K, (t + 3) * 32, tid, wid);
      stage_op128(Bubase + ((t + 3) & 3) * 4096, Bu, n0, K, (t + 3) * 32, tid, wid);
    }
    BARRIER();
    WAIT_LGKM0();
    __builtin_amdgcn_s_setprio(1);
#pragma unroll
    for (int m = 0; m < 2; ++m)
#pragma unroll
      for (int n = 0; n < 4; ++n) {
        accg[m + 2][n] = __builtin_amdgcn_mfma_f32_16x16x32_bf16(af[m], bg[n],
                                                                 accg[m + 2][n], 0, 0, 0);
        accu[m + 2][n] = __builtin_amdgcn_mfma_f32_16x16x32_bf16(af[m], bu[n],
                                                                 accu[m + 2][n], 0, 0, 0);
      }
    __builtin_amdgcn_s_setprio(0);
    __builtin_amdgcn_sched_barrier(0);
    tile_end_wait(NT - 1 - t);
    BARRIER();
  }

#pragma unroll
  for (int m = 0; m < 4; ++m) {
    int rbase = m0 + wm * 64 + m * 16 + q * 4;
#pragma unroll
    for (int n = 0; n < 4; ++n) {
      int col = n0 + wn * 64 + n * 16 + lr;
#pragma unroll
      for (int r = 0; r < 4; ++r) {
        float g = accg[m][n][r];
        float h = (g / (1.f + __expf(-g))) * accu[m][n][r];
        H[(size_t)(rbase + r) * N + col] = f2bf(h);
      }
    }
  }
}

// ---------------- routing: per-token 2x(64x64 matvec) + top8 + pair top8 ----------------
__global__ __launch_bounds__(256) void routing_kernel(const float* __restrict__ Q,
                                                      const float* __restrict__ keys,
                                                      int* __restrict__ topi,
                                                      float* __restrict__ topw) {
  __shared__ float k0s[64 * 64];
  __shared__ float k1s[64 * 64];
  for (int i = threadIdx.x; i < 64 * 64; i += 256) {
    k0s[i] = keys[i];
    k1s[i] = keys[64 * 64 + i];
  }
  __syncthreads();
  const int lane = threadIdx.x & 63, wid = threadIdx.x >> 6;
  const int gw = blockIdx.x * 4 + wid;  // 1024 waves total
  const float NEG = -__builtin_inff();

  for (int n = gw; n < NTOK; n += 1024) {
    int cbase = (n & 1) * 64;
    float qx = Q[(size_t)(n >> 1) * RET + cbase + lane];
    float qy = Q[(size_t)(NTOK / 2 + (n >> 1)) * RET + cbase + lane];
    float rx = 0.f, ry = 0.f;
#pragma unroll 8
    for (int d = 0; d < 64; ++d) {
      rx += __shfl(qx, d) * k0s[d * 64 + lane];
      ry += __shfl(qy, d) * k1s[d * 64 + lane];
    }
    float mvx = rx, mvy = ry;
    float keptx = 0.f, kepty = 0.f;
    int keptix = 0, keptiy = 0;
#pragma unroll
    for (int a = 0; a < 8; ++a) {
      float v = mvx; int ii = lane;
#pragma unroll
      for (int off = 32; off; off >>= 1) {
        float ov = __shfl_xor(v, off); int oi = __shfl_xor(ii, off);
        if (ov > v || (ov == v && oi < ii)) { v = ov; ii = oi; }
      }
      if (lane == a) { keptx = v; keptix = ii; }
      if (lane == ii) mvx = NEG;
      float w = mvy; int jj = lane;
#pragma unroll
      for (int off = 32; off; off >>= 1) {
        float ow = __shfl_xor(w, off); int oj = __shfl_xor(jj, off);
        if (ow > w || (ow == w && oj < jj)) { w = ow; jj = oj; }
      }
      if (lane == a) { kepty = w; keptiy = jj; }
      if (lane == jj) mvy = NEG;
    }
    float sa = __shfl(keptx, lane >> 3), sb = __shfl(kepty, lane & 7);
    int ia = __shfl(keptix, lane >> 3), ib = __shfl(keptiy, lane & 7);
    float mv = sa + sb;
    int pe = ia * NKEYS + ib;
    float maxs = 0.f, denom = 0.f, kw = 0.f;
    int ke = 0;
#pragma unroll
    for (int a = 0; a < 8; ++a) {
      float v = mv; int pos = lane; int e = pe;
#pragma unroll
      for (int off = 32; off; off >>= 1) {
        float ov = __shfl_xor(v, off);
        int opos = __shfl_xor(pos, off);
        int oe = __shfl_xor(e, off);
        if (ov > v || (ov == v && opos < pos)) { v = ov; pos = opos; e = oe; }
      }
      if (a == 0) maxs = v;
      denom += __expf(v - maxs);
      if (lane == a) { kw = __expf(v - maxs); ke = e; }
      if (lane == pos) mv = NEG;
    }
    if (lane < 8) {
      topw[(size_t)n * 8 + lane] = kw / denom;
      topi[(size_t)n * 8 + lane] = ke;
    }
  }
}

// ---------------- expert branch v2: batched dots, one reduction round-trip ---
__global__ __launch_bounds__(256) void expert_kernel(const float* __restrict__ X,
                                                     const float* __restrict__ de,
                                                     const float* __restrict__ ue,
                                                     const int* __restrict__ topi,
                                                     const float* __restrict__ topw,
                                                     float* __restrict__ out) {
  const int n = blockIdx.x, t = threadIdx.x;
  const int lane = t & 63, wid = t >> 6;
  __shared__ float red[4][8];
  __shared__ int eidx[8];
  __shared__ float ewt[8];
  if (t < 8) {
    eidx[t] = topi[(size_t)n * 8 + t];
    ewt[t] = topw[(size_t)n * 8 + t];
  }
  __syncthreads();
  const float* x = X + (size_t)n * HIDDEN + t * 8;
  float4 x0 = *(const float4*)x, x1 = *(const float4*)(x + 4);
  float p[8];
#pragma unroll
  for (int k = 0; k < 8; ++k) {
    const float* dr = de + (size_t)eidx[k] * HIDDEN + t * 8;
    float4 d0 = *(const float4*)dr, d1 = *(const float4*)(dr + 4);
    p[k] = x0.x * d0.x + x0.y * d0.y + x0.z * d0.z + x0.w * d0.w +
           x1.x * d1.x + x1.y * d1.y + x1.z * d1.z + x1.w * d1.w;
  }
#pragma unroll
  for (int k = 0; k < 8; ++k)
#pragma unroll
    for (int off = 32; off; off >>= 1) p[k] += __shfl_xor(p[k], off);
  if (lane == 0) {
#pragma unroll
    for (int k = 0; k < 8; ++k) red[wid][k] = p[k];
  }
  __syncthreads();
  float coef[8];
#pragma unroll
  for (int k = 0; k < 8; ++k) {
    float s = red[0][k] + red[1][k] + red[2][k] + red[3][k];
    coef[k] = (s / (1.f + __expf(-s))) * ewt[k];
  }
  float a0 = 0, a1 = 0, a2 = 0, a3 = 0, a4 = 0, a5 = 0, a6 = 0, a7 = 0;
#pragma unroll
  for (int k = 0; k < 8; ++k) {
    const float* ur = ue + (size_t)eidx[k] * HIDDEN + t * 8;
    float4 u0 = *(const float4*)ur, u1 = *(const float4*)(ur + 4);
    float c = coef[k];
    a0 += c * u0.x; a1 += c * u0.y; a2 += c * u0.z; a3 += c * u0.w;
    a4 += c * u1.x; a5 += c * u1.y; a6 += c * u1.z; a7 += c * u1.w;
  }
  float* op = out + (size_t)n * HIDDEN + t * 8;
  *(float4*)op = make_float4(a0, a1, a2, a3);
  *(float4*)(op + 4) = make_float4(a4, a5, a6, a7);
}

extern "C" void kernel_launch(void* const* d_in, const int* in_sizes, int n_in,
                              void* d_out, int out_size, void* d_ws, size_t ws_size,
                              hipStream_t stream) {
  const float* X    = (const float*)d_in[0];
  const float* Wq   = (const float*)d_in[1];
  const float* keys = (const float*)d_in[2];
  const float* de   = (const float*)d_in[3];
  const float* ue   = (const float*)d_in[4];
  const float* Wg   = (const float*)d_in[5];
  const float* Wu   = (const float*)d_in[6];
  const float* Wd   = (const float*)d_in[7];
  float* out = (float*)d_out;

  char* ws = (char*)d_ws;
  size_t o = 0;
  unsigned short* xb  = (unsigned short*)(ws + o); o += (size_t)NTOK * HIDDEN * 2;
  unsigned short* wgt = (unsigned short*)(ws + o); o += (size_t)HIDDEN * INTER * 2;
  unsigned short* wut = (unsigned short*)(ws + o); o += (size_t)HIDDEN * INTER * 2;
  unsigned short* wdt = (unsigned short*)(ws + o); o += (size_t)HIDDEN * INTER * 2;
  unsigned short* hbuf= (unsigned short*)(ws + o); o += (size_t)NTOK * INTER * 2;
  unsigned short* wqt = (unsigned short*)(ws + o); o += (size_t)RET * HIDDEN * 2;
  float* Q            = (float*)(ws + o);          o += (size_t)NTOK * RET * 4;
  int* topi           = (int*)(ws + o);            o += (size_t)NTOK * TOPK * 4;
  float* topw         = (float*)(ws + o);          o += (size_t)NTOK * TOPK * 4;

  // one-time: allow 128 KiB dynamic LDS on the pipelined GEMMs
  static bool attr_done = false;
  if (!attr_done) {
    auto kd = gemm256<EPI_ADDF32>;
    auto kg = gateup256;
    (void)hipFuncSetAttribute(reinterpret_cast<const void*>(kd),
                              hipFuncAttributeMaxDynamicSharedMemorySize, 131072);
    (void)hipFuncSetAttribute(reinterpret_cast<const void*>(kg),
                              hipFuncAttributeMaxDynamicSharedMemorySize, 131072);
    attr_done = true;
  }

  // prep: bf16 conversions / weight transposes
  cvt_bf16<<<4096, 256, 0, stream>>>(X, xb, NTOK * HIDDEN / 4);
  transpose_cvt<<<dim3(INTER / 32, HIDDEN / 32), dim3(32, 8), 0, stream>>>(Wg, wgt, HIDDEN, INTER);
  transpose_cvt<<<dim3(INTER / 32, HIDDEN / 32), dim3(32, 8), 0, stream>>>(Wu, wut, HIDDEN, INTER);
  transpose_cvt<<<dim3(HIDDEN / 32, INTER / 32), dim3(32, 8), 0, stream>>>(Wd, wdt, INTER, HIDDEN);
  transpose_cvt<<<dim3(RET / 32, HIDDEN / 32), dim3(32, 8), 0, stream>>>(Wq, wqt, HIDDEN, RET);

  // routing branch
  gemm_bt<EPI_F32><<<dim3(1, NTOK / 128), 256, 0, stream>>>(xb, wqt, Q,
                                                            NTOK, RET, HIDDEN);
  routing_kernel<<<256, 256, 0, stream>>>(Q, keys, topi, topw);
  expert_kernel<<<NTOK, 256, 0, stream>>>(X, de, ue, topi, topw, out);

  // dense SwiGLU MLP branch (deep-pipelined 256-tile GEMMs)
  gateup256<<<dim3(INTER / 128, NTOK / 256), 512, 131072, stream>>>(
      xb, wgt, wut, hbuf, INTER, HIDDEN);
  gemm256<EPI_ADDF32><<<dim3(HIDDEN / 256, NTOK / 256), 512, 131072, stream>>>(
      hbuf, wdt, out, HIDDEN, INTER);
}

// Round 4
// 1501.168 us; speedup vs baseline: 1.0480x; 1.0415x over previous
//
#include <hip/hip_runtime.h>
#include <cstdint>
#include <cstddef>

#define HIDDEN 2048
#define INTER 8192
#define NTOK 8192
#define RET 128
#define NKEYS 64
#define TOPK 8

typedef __bf16 bf16_t;
typedef bf16_t bf16x8 __attribute__((ext_vector_type(8)));
typedef float floatx4 __attribute__((ext_vector_type(4)));

#define BARRIER() asm volatile("s_barrier" ::: "memory")
#define WAIT_LGKM0()                                     \
  do {                                                   \
    asm volatile("s_waitcnt lgkmcnt(0)" ::: "memory");   \
    __builtin_amdgcn_sched_barrier(0);                   \
  } while (0)
#define WAIT_VM6() asm volatile("s_waitcnt vmcnt(6)" ::: "memory")
#define WAIT_VM0() asm volatile("s_waitcnt vmcnt(0)" ::: "memory")

// Ring-3 tile-end drain. Per wave, each K-tile stages 6 VMEM ops (A:4 + B:2).
// Steady state at end of tile t: stage(t+1) [6, issued during t-1] +
// stage(t+2) [6, issued during t] outstanding -> vmcnt(6) lands stage(t+1),
// which tile t+1 reads. Endgame: rem==1 -> vmcnt(0) (only stage(NT-1) left),
// rem==0 -> nothing. (R1 bug class: the count must follow actual in-flight.)
__device__ inline void tile_end_wait3(int rem) {
  if (rem >= 2) WAIT_VM6();
  else if (rem == 1) WAIT_VM0();
}

__device__ inline unsigned short f2bf(float f) {
  union { float f; unsigned u; } v; v.f = f;
  unsigned r = v.u + 0x7FFFu + ((v.u >> 16) & 1u);  // RNE
  return (unsigned short)(r >> 16);
}

// async global->LDS, 16B per lane. lds must be the wave-uniform base; HW puts
// lane i's 16B at base + i*16.
__device__ inline void gld_lds16(unsigned short* lds, const unsigned short* g) {
  auto* l3 = reinterpret_cast<__attribute__((address_space(3))) unsigned int*>(
      reinterpret_cast<uintptr_t>(lds));
  auto* g1 = reinterpret_cast<const __attribute__((address_space(1))) unsigned int*>(
      reinterpret_cast<uintptr_t>(g));
  __builtin_amdgcn_global_load_lds(g1, l3, 16, 0, 0);
}

// XCD-aware block remap: contiguous column band per XCD, serpentine traversal.
// Only applies when gridDim.x % 8 == 0.
__device__ inline void xcd_map(int gx, int gy, int& bx, int& by) {
  if ((gx & 7) != 0) return;
  int lin = by * gx + bx;
  int W = gx >> 3;
  int xcd = lin & 7;
  int j = lin >> 3;
  int r = j / W, c = j % W;
  if (r & 1) c = W - 1 - c;
  bx = xcd * W + c;
  by = r;
}

// Stage a ROWS x 64 bf16 tile into LDS. 128-B rows, 8 chunk slots of 16 B.
// Linear dest + inverse-swizzled source: chunk cc stored at slot cc^(row&7).
// This is R0's measured-conflict-free geometry (R2's 64-B rows cost ~4 cy per
// ds_read_b128: SQ_LDS_BANK_CONFLICT 0 -> 5.03e7, deterministic).
template <int ROWS>
__device__ inline void stage_tile(unsigned short* ldsbuf, const unsigned short* g,
                                  int rows0, int K, int kt, int tid, int wid) {
#pragma unroll
  for (int s = 0; s < ROWS / 64; ++s) {
    int c = s * 512 + tid;
    int row = c >> 3, cc = (c & 7) ^ (row & 7);
    gld_lds16(ldsbuf + (size_t)(s * 512 + wid * 64) * 8,
              g + (size_t)(rows0 + row) * K + kt + cc * 8);
  }
}

// ---------------- fp32 -> bf16 convert (contiguous) ----------------
__global__ __launch_bounds__(256) void cvt_bf16(const float* __restrict__ in,
                                                unsigned short* __restrict__ out,
                                                int count4) {
  for (int i = blockIdx.x * blockDim.x + threadIdx.x; i < count4;
       i += gridDim.x * blockDim.x) {
    float4 v = reinterpret_cast<const float4*>(in)[i];
    ushort4 o;
    o.x = f2bf(v.x); o.y = f2bf(v.y); o.z = f2bf(v.z); o.w = f2bf(v.w);
    reinterpret_cast<ushort4*>(out)[i] = o;
  }
}

// ---------------- fp32 [R][C] -> bf16 [C][R] transpose-convert ----------------
__global__ __launch_bounds__(256) void transpose_cvt(const float* __restrict__ in,
                                                     unsigned short* __restrict__ out,
                                                     int R, int C) {
  __shared__ float tile[32][33];
  int c0 = blockIdx.x * 32, r0 = blockIdx.y * 32;
  int tx = threadIdx.x, ty = threadIdx.y;  // block (32,8)
#pragma unroll
  for (int it = 0; it < 4; ++it)
    tile[ty + it * 8][tx] = in[(size_t)(r0 + ty + it * 8) * C + c0 + tx];
  __syncthreads();
#pragma unroll
  for (int it = 0; it < 4; ++it)
    out[(size_t)(c0 + ty + it * 8) * R + r0 + tx] = f2bf(tile[tx][ty + it * 8]);
}

// ---------------- legacy 128x128 bf16 GEMM (kept for the small Q proj) -------
enum { EPI_F32 = 0, EPI_ADDF32 = 3 };

template <int MODE>
__global__ __launch_bounds__(256) void gemm_bt(const unsigned short* __restrict__ A,
                                               const unsigned short* __restrict__ B,
                                               float* __restrict__ Cf,
                                               int M, int N, int K) {
  __shared__ unsigned short As[128 * 64];
  __shared__ unsigned short Bs[128 * 64];
  const int tid = threadIdx.x;
  const int lane = tid & 63, wid = tid >> 6;
  const int wm = wid >> 1, wn = wid & 1;
  int bx = blockIdx.x, by = blockIdx.y;
  xcd_map(gridDim.x, gridDim.y, bx, by);
  const int m0 = by * 128, n0 = bx * 128;
  const int lr = lane & 15, q = lane >> 4;
  const int swz = lr & 7;

  floatx4 acc[4][4];
#pragma unroll
  for (int i = 0; i < 4; ++i)
#pragma unroll
    for (int j = 0; j < 4; ++j) acc[i][j] = (floatx4){0.f, 0.f, 0.f, 0.f};

  for (int k0 = 0; k0 < K; k0 += 64) {
#pragma unroll
    for (int s = 0; s < 4; ++s) {
      int c = s * 256 + wid * 64 + lane;
      int row = c >> 3, cc = (c & 7) ^ (row & 7);
      gld_lds16(&As[(s * 256 + wid * 64) * 8],
                A + (size_t)(m0 + row) * K + k0 + cc * 8);
      gld_lds16(&Bs[(s * 256 + wid * 64) * 8],
                B + (size_t)(n0 + row) * K + k0 + cc * 8);
    }
    __syncthreads();
#pragma unroll
    for (int kc = 0; kc < 2; ++kc) {
      const int coff = ((kc * 4 + q) ^ swz) * 8;
      bf16x8 af[4], bfv[4];
#pragma unroll
      for (int t = 0; t < 4; ++t) {
        af[t] = *reinterpret_cast<const bf16x8*>(
            &As[(wm * 64 + t * 16 + lr) * 64 + coff]);
        bfv[t] = *reinterpret_cast<const bf16x8*>(
            &Bs[(wn * 64 + t * 16 + lr) * 64 + coff]);
      }
#pragma unroll
      for (int i = 0; i < 4; ++i)
#pragma unroll
        for (int j = 0; j < 4; ++j)
          acc[i][j] = __builtin_amdgcn_mfma_f32_16x16x32_bf16(af[i], bfv[j],
                                                              acc[i][j], 0, 0, 0);
    }
    __syncthreads();
  }

#pragma unroll
  for (int i = 0; i < 4; ++i) {
    int rbase = m0 + wm * 64 + i * 16 + q * 4;
#pragma unroll
    for (int j = 0; j < 4; ++j) {
      int col = n0 + wn * 64 + j * 16 + lr;
#pragma unroll
      for (int r = 0; r < 4; ++r) {
        size_t idx = (size_t)(rbase + r) * N + col;
        float v = acc[i][j][r];
        if (MODE == EPI_F32) Cf[idx] = v;
        else Cf[idx] = v + Cf[idx];
      }
    }
  }
}

// ---------------- ring-3 pipelined down-proj GEMM: C[M,N] += A[M,K]*B[N,K]^T --
// BM=256, BN=128, BK=64, 8 waves (4M x 2N, 64x64/wave). LDS: 3 ring slots x
// (A 32KB + B 16KB) = 144 KiB. While computing tile t, stage tile t+2;
// tile-end counted wait (vmcnt 6 -> 0 -> none). 128-B LDS rows + 3-bit XOR
// swizzle (proven 0-conflict in R0).
template <int MODE>
__global__ __launch_bounds__(512, 2) void gemm_dp(const unsigned short* __restrict__ A,
                                                  const unsigned short* __restrict__ B,
                                                  float* __restrict__ Cf,
                                                  int N, int K) {
  extern __shared__ unsigned short sm[];
  const int tid = threadIdx.x;
  const int lane = tid & 63, wid = tid >> 6;
  const int wm = wid >> 1, wn = wid & 1;
  int bx = blockIdx.x, by = blockIdx.y;
  xcd_map(gridDim.x, gridDim.y, bx, by);
  const int m0 = by * 256, n0 = bx * 128;
  const int lr = lane & 15, q = lane >> 4;
  const int swz = lr & 7;
  const int SLOT = 24576;  // shorts per ring slot: A 16384 + B 8192
  const int NT = K >> 6;

  floatx4 acc[4][4];
#pragma unroll
  for (int i = 0; i < 4; ++i)
#pragma unroll
    for (int j = 0; j < 4; ++j) acc[i][j] = (floatx4){0.f, 0.f, 0.f, 0.f};

  // prologue: stage tiles 0,1 (12 loads/wave); vmcnt(6) lands tile 0.
#pragma unroll
  for (int tt = 0; tt < 2; ++tt) {
    unsigned short* slot = sm + tt * SLOT;
    stage_tile<256>(slot, A, m0, K, tt * 64, tid, wid);
    stage_tile<128>(slot + 16384, B, n0, K, tt * 64, tid, wid);
  }
  WAIT_VM6();
  BARRIER();

  for (int t = 0; t < NT; ++t) {
    unsigned short* slot = sm + (t % 3) * SLOT;
    const unsigned short* As = slot;
    const unsigned short* Bs = slot + 16384;
    unsigned short* nslot = sm + ((t + 2) % 3) * SLOT;
#pragma unroll
    for (int kc = 0; kc < 2; ++kc) {
      const int coff = ((kc * 4 + q) ^ swz) * 8;
      bf16x8 af[4], bfv[4];
#pragma unroll
      for (int m = 0; m < 4; ++m)
        af[m] = *reinterpret_cast<const bf16x8*>(
            &As[(wm * 64 + m * 16 + lr) * 64 + coff]);
#pragma unroll
      for (int n = 0; n < 4; ++n)
        bfv[n] = *reinterpret_cast<const bf16x8*>(
            &Bs[(wn * 64 + n * 16 + lr) * 64 + coff]);
      if (t + 2 < NT) {
        if (kc == 0) stage_tile<256>(nslot, A, m0, K, (t + 2) * 64, tid, wid);
        else stage_tile<128>(nslot + 16384, B, n0, K, (t + 2) * 64, tid, wid);
      }
      BARRIER();
      WAIT_LGKM0();
      __builtin_amdgcn_s_setprio(1);
#pragma unroll
      for (int m = 0; m < 4; ++m)
#pragma unroll
        for (int n = 0; n < 4; ++n)
          acc[m][n] = __builtin_amdgcn_mfma_f32_16x16x32_bf16(af[m], bfv[n],
                                                              acc[m][n], 0, 0, 0);
      __builtin_amdgcn_s_setprio(0);
      __builtin_amdgcn_sched_barrier(0);
      if (kc == 1) tile_end_wait3(NT - 1 - t);
      BARRIER();
    }
  }

  // epilogue: C/D layout col=lane&15, row=(lane>>4)*4+reg
#pragma unroll
  for (int m = 0; m < 4; ++m) {
    int rbase = m0 + wm * 64 + m * 16 + q * 4;
#pragma unroll
    for (int n = 0; n < 4; ++n) {
      int col = n0 + wn * 64 + n * 16 + lr;
#pragma unroll
      for (int r = 0; r < 4; ++r) {
        size_t idx = (size_t)(rbase + r) * N + col;
        float v = acc[m][n][r];
        if (MODE == EPI_F32) Cf[idx] = v;
        else Cf[idx] = v + Cf[idx];  // += expert states already in d_out
      }
    }
  }
}

// ---------------- ring-3 pipelined fused gate+up GEMM ------------------------
// BM=256, BN=64, BK=64, 8 waves (4M x 2N, 64x32/wave; dual acc = 64 VGPR).
// LDS: 3 x (A 32KB + Bg 8KB + Bu 8KB) = 144 KiB. Same schedule as gemm_dp.
__global__ __launch_bounds__(512, 2) void gateup_p3(const unsigned short* __restrict__ A,
                                                    const unsigned short* __restrict__ Bg,
                                                    const unsigned short* __restrict__ Bu,
                                                    unsigned short* __restrict__ H,
                                                    int N, int K) {
  extern __shared__ unsigned short sm[];
  const int tid = threadIdx.x;
  const int lane = tid & 63, wid = tid >> 6;
  const int wm = wid >> 1, wn = wid & 1;
  int bx = blockIdx.x, by = blockIdx.y;
  xcd_map(gridDim.x, gridDim.y, bx, by);
  const int m0 = by * 256, n0 = bx * 64;
  const int lr = lane & 15, q = lane >> 4;
  const int swz = lr & 7;
  const int SLOT = 24576;  // shorts: A 16384 + Bg 4096 + Bu 4096
  const int NT = K >> 6;

  floatx4 accg[4][2], accu[4][2];
#pragma unroll
  for (int i = 0; i < 4; ++i)
#pragma unroll
    for (int j = 0; j < 2; ++j) {
      accg[i][j] = (floatx4){0.f, 0.f, 0.f, 0.f};
      accu[i][j] = (floatx4){0.f, 0.f, 0.f, 0.f};
    }

#pragma unroll
  for (int tt = 0; tt < 2; ++tt) {
    unsigned short* slot = sm + tt * SLOT;
    stage_tile<256>(slot, A, m0, K, tt * 64, tid, wid);
    stage_tile<64>(slot + 16384, Bg, n0, K, tt * 64, tid, wid);
    stage_tile<64>(slot + 20480, Bu, n0, K, tt * 64, tid, wid);
  }
  WAIT_VM6();
  BARRIER();

  for (int t = 0; t < NT; ++t) {
    unsigned short* slot = sm + (t % 3) * SLOT;
    const unsigned short* As = slot;
    const unsigned short* Bgs = slot + 16384;
    const unsigned short* Bus = slot + 20480;
    unsigned short* nslot = sm + ((t + 2) % 3) * SLOT;
#pragma unroll
    for (int kc = 0; kc < 2; ++kc) {
      const int coff = ((kc * 4 + q) ^ swz) * 8;
      bf16x8 af[4], bg[2], bu[2];
#pragma unroll
      for (int m = 0; m < 4; ++m)
        af[m] = *reinterpret_cast<const bf16x8*>(
            &As[(wm * 64 + m * 16 + lr) * 64 + coff]);
#pragma unroll
      for (int n = 0; n < 2; ++n) {
        bg[n] = *reinterpret_cast<const bf16x8*>(
            &Bgs[(wn * 32 + n * 16 + lr) * 64 + coff]);
        bu[n] = *reinterpret_cast<const bf16x8*>(
            &Bus[(wn * 32 + n * 16 + lr) * 64 + coff]);
      }
      if (t + 2 < NT) {
        if (kc == 0) {
          stage_tile<256>(nslot, A, m0, K, (t + 2) * 64, tid, wid);
        } else {
          stage_tile<64>(nslot + 16384, Bg, n0, K, (t + 2) * 64, tid, wid);
          stage_tile<64>(nslot + 20480, Bu, n0, K, (t + 2) * 64, tid, wid);
        }
      }
      BARRIER();
      WAIT_LGKM0();
      __builtin_amdgcn_s_setprio(1);
#pragma unroll
      for (int m = 0; m < 4; ++m)
#pragma unroll
        for (int n = 0; n < 2; ++n) {
          accg[m][n] = __builtin_amdgcn_mfma_f32_16x16x32_bf16(af[m], bg[n],
                                                               accg[m][n], 0, 0, 0);
          accu[m][n] = __builtin_amdgcn_mfma_f32_16x16x32_bf16(af[m], bu[n],
                                                               accu[m][n], 0, 0, 0);
        }
      __builtin_amdgcn_s_setprio(0);
      __builtin_amdgcn_sched_barrier(0);
      if (kc == 1) tile_end_wait3(NT - 1 - t);
      BARRIER();
    }
  }

#pragma unroll
  for (int m = 0; m < 4; ++m) {
    int rbase = m0 + wm * 64 + m * 16 + q * 4;
#pragma unroll
    for (int n = 0; n < 2; ++n) {
      int col = n0 + wn * 32 + n * 16 + lr;
#pragma unroll
      for (int r = 0; r < 4; ++r) {
        float g = accg[m][n][r];
        float h = (g / (1.f + __expf(-g))) * accu[m][n][r];
        H[(size_t)(rbase + r) * N + col] = f2bf(h);
      }
    }
  }
}

// ---------------- routing: per-token 2x(64x64 matvec) + top8 + pair top8 ----------------
__global__ __launch_bounds__(256) void routing_kernel(const float* __restrict__ Q,
                                                      const float* __restrict__ keys,
                                                      int* __restrict__ topi,
                                                      float* __restrict__ topw) {
  __shared__ float k0s[64 * 64];
  __shared__ float k1s[64 * 64];
  for (int i = threadIdx.x; i < 64 * 64; i += 256) {
    k0s[i] = keys[i];
    k1s[i] = keys[64 * 64 + i];
  }
  __syncthreads();
  const int lane = threadIdx.x & 63, wid = threadIdx.x >> 6;
  const int gw = blockIdx.x * 4 + wid;  // 1024 waves total
  const float NEG = -__builtin_inff();

  for (int n = gw; n < NTOK; n += 1024) {
    int cbase = (n & 1) * 64;
    float qx = Q[(size_t)(n >> 1) * RET + cbase + lane];
    float qy = Q[(size_t)(NTOK / 2 + (n >> 1)) * RET + cbase + lane];
    float rx = 0.f, ry = 0.f;
#pragma unroll 8
    for (int d = 0; d < 64; ++d) {
      rx += __shfl(qx, d) * k0s[d * 64 + lane];
      ry += __shfl(qy, d) * k1s[d * 64 + lane];
    }
    float mvx = rx, mvy = ry;
    float keptx = 0.f, kepty = 0.f;
    int keptix = 0, keptiy = 0;
#pragma unroll
    for (int a = 0; a < 8; ++a) {
      float v = mvx; int ii = lane;
#pragma unroll
      for (int off = 32; off; off >>= 1) {
        float ov = __shfl_xor(v, off); int oi = __shfl_xor(ii, off);
        if (ov > v || (ov == v && oi < ii)) { v = ov; ii = oi; }
      }
      if (lane == a) { keptx = v; keptix = ii; }
      if (lane == ii) mvx = NEG;
      float w = mvy; int jj = lane;
#pragma unroll
      for (int off = 32; off; off >>= 1) {
        float ow = __shfl_xor(w, off); int oj = __shfl_xor(jj, off);
        if (ow > w || (ow == w && oj < jj)) { w = ow; jj = oj; }
      }
      if (lane == a) { kepty = w; keptiy = jj; }
      if (lane == jj) mvy = NEG;
    }
    float sa = __shfl(keptx, lane >> 3), sb = __shfl(kepty, lane & 7);
    int ia = __shfl(keptix, lane >> 3), ib = __shfl(keptiy, lane & 7);
    float mv = sa + sb;
    int pe = ia * NKEYS + ib;
    float maxs = 0.f, denom = 0.f, kw = 0.f;
    int ke = 0;
#pragma unroll
    for (int a = 0; a < 8; ++a) {
      float v = mv; int pos = lane; int e = pe;
#pragma unroll
      for (int off = 32; off; off >>= 1) {
        float ov = __shfl_xor(v, off);
        int opos = __shfl_xor(pos, off);
        int oe = __shfl_xor(e, off);
        if (ov > v || (ov == v && opos < pos)) { v = ov; pos = opos; e = oe; }
      }
      if (a == 0) maxs = v;
      denom += __expf(v - maxs);
      if (lane == a) { kw = __expf(v - maxs); ke = e; }
      if (lane == pos) mv = NEG;
    }
    if (lane < 8) {
      topw[(size_t)n * 8 + lane] = kw / denom;
      topi[(size_t)n * 8 + lane] = ke;
    }
  }
}

// ---------------- expert branch v2: batched dots, one reduction round-trip ---
__global__ __launch_bounds__(256) void expert_kernel(const float* __restrict__ X,
                                                     const float* __restrict__ de,
                                                     const float* __restrict__ ue,
                                                     const int* __restrict__ topi,
                                                     const float* __restrict__ topw,
                                                     float* __restrict__ out) {
  const int n = blockIdx.x, t = threadIdx.x;
  const int lane = t & 63, wid = t >> 6;
  __shared__ float red[4][8];
  __shared__ int eidx[8];
  __shared__ float ewt[8];
  if (t < 8) {
    eidx[t] = topi[(size_t)n * 8 + t];
    ewt[t] = topw[(size_t)n * 8 + t];
  }
  __syncthreads();
  const float* x = X + (size_t)n * HIDDEN + t * 8;
  float4 x0 = *(const float4*)x, x1 = *(const float4*)(x + 4);
  float p[8];
#pragma unroll
  for (int k = 0; k < 8; ++k) {
    const float* dr = de + (size_t)eidx[k] * HIDDEN + t * 8;
    float4 d0 = *(const float4*)dr, d1 = *(const float4*)(dr + 4);
    p[k] = x0.x * d0.x + x0.y * d0.y + x0.z * d0.z + x0.w * d0.w +
           x1.x * d1.x + x1.y * d1.y + x1.z * d1.z + x1.w * d1.w;
  }
#pragma unroll
  for (int k = 0; k < 8; ++k)
#pragma unroll
    for (int off = 32; off; off >>= 1) p[k] += __shfl_xor(p[k], off);
  if (lane == 0) {
#pragma unroll
    for (int k = 0; k < 8; ++k) red[wid][k] = p[k];
  }
  __syncthreads();
  float coef[8];
#pragma unroll
  for (int k = 0; k < 8; ++k) {
    float s = red[0][k] + red[1][k] + red[2][k] + red[3][k];
    coef[k] = (s / (1.f + __expf(-s))) * ewt[k];
  }
  float a0 = 0, a1 = 0, a2 = 0, a3 = 0, a4 = 0, a5 = 0, a6 = 0, a7 = 0;
#pragma unroll
  for (int k = 0; k < 8; ++k) {
    const float* ur = ue + (size_t)eidx[k] * HIDDEN + t * 8;
    float4 u0 = *(const float4*)ur, u1 = *(const float4*)(ur + 4);
    float c = coef[k];
    a0 += c * u0.x; a1 += c * u0.y; a2 += c * u0.z; a3 += c * u0.w;
    a4 += c * u1.x; a5 += c * u1.y; a6 += c * u1.z; a7 += c * u1.w;
  }
  float* op = out + (size_t)n * HIDDEN + t * 8;
  *(float4*)op = make_float4(a0, a1, a2, a3);
  *(float4*)(op + 4) = make_float4(a4, a5, a6, a7);
}

extern "C" void kernel_launch(void* const* d_in, const int* in_sizes, int n_in,
                              void* d_out, int out_size, void* d_ws, size_t ws_size,
                              hipStream_t stream) {
  const float* X    = (const float*)d_in[0];
  const float* Wq   = (const float*)d_in[1];
  const float* keys = (const float*)d_in[2];
  const float* de   = (const float*)d_in[3];
  const float* ue   = (const float*)d_in[4];
  const float* Wg   = (const float*)d_in[5];
  const float* Wu   = (const float*)d_in[6];
  const float* Wd   = (const float*)d_in[7];
  float* out = (float*)d_out;

  char* ws = (char*)d_ws;
  size_t o = 0;
  unsigned short* xb  = (unsigned short*)(ws + o); o += (size_t)NTOK * HIDDEN * 2;
  unsigned short* wgt = (unsigned short*)(ws + o); o += (size_t)HIDDEN * INTER * 2;
  unsigned short* wut = (unsigned short*)(ws + o); o += (size_t)HIDDEN * INTER * 2;
  unsigned short* wdt = (unsigned short*)(ws + o); o += (size_t)HIDDEN * INTER * 2;
  unsigned short* hbuf= (unsigned short*)(ws + o); o += (size_t)NTOK * INTER * 2;
  unsigned short* wqt = (unsigned short*)(ws + o); o += (size_t)RET * HIDDEN * 2;
  float* Q            = (float*)(ws + o);          o += (size_t)NTOK * RET * 4;
  int* topi           = (int*)(ws + o);            o += (size_t)NTOK * TOPK * 4;
  float* topw         = (float*)(ws + o);          o += (size_t)NTOK * TOPK * 4;

  // one-time: allow 144 KiB dynamic LDS on the pipelined GEMMs
  static bool attr_done = false;
  if (!attr_done) {
    auto kd = gemm_dp<EPI_ADDF32>;
    auto kg = gateup_p3;
    (void)hipFuncSetAttribute(reinterpret_cast<const void*>(kd),
                              hipFuncAttributeMaxDynamicSharedMemorySize, 147456);
    (void)hipFuncSetAttribute(reinterpret_cast<const void*>(kg),
                              hipFuncAttributeMaxDynamicSharedMemorySize, 147456);
    attr_done = true;
  }

  // prep: bf16 conversions / weight transposes
  cvt_bf16<<<4096, 256, 0, stream>>>(X, xb, NTOK * HIDDEN / 4);
  transpose_cvt<<<dim3(INTER / 32, HIDDEN / 32), dim3(32, 8), 0, stream>>>(Wg, wgt, HIDDEN, INTER);
  transpose_cvt<<<dim3(INTER / 32, HIDDEN / 32), dim3(32, 8), 0, stream>>>(Wu, wut, HIDDEN, INTER);
  transpose_cvt<<<dim3(HIDDEN / 32, INTER / 32), dim3(32, 8), 0, stream>>>(Wd, wdt, INTER, HIDDEN);
  transpose_cvt<<<dim3(RET / 32, HIDDEN / 32), dim3(32, 8), 0, stream>>>(Wq, wqt, HIDDEN, RET);

  // routing branch
  gemm_bt<EPI_F32><<<dim3(1, NTOK / 128), 256, 0, stream>>>(xb, wqt, Q,
                                                            NTOK, RET, HIDDEN);
  routing_kernel<<<256, 256, 0, stream>>>(Q, keys, topi, topw);
  expert_kernel<<<NTOK, 256, 0, stream>>>(X, de, ue, topi, topw, out);

  // dense SwiGLU MLP branch (ring-3 pipelined GEMMs)
  gateup_p3<<<dim3(INTER / 64, NTOK / 256), 512, 147456, stream>>>(
      xb, wgt, wut, hbuf, INTER, HIDDEN);
  gemm_dp<EPI_ADDF32><<<dim3(HIDDEN / 128, NTOK / 256), 512, 147456, stream>>>(
      hbuf, wdt, out, HIDDEN, INTER);
}